// Round 2
// baseline (4640.114 us; speedup 1.0000x reference)
//
#include <hip/hip_runtime.h>
#include <stdint.h>

#define DEVINL __device__ __forceinline__

typedef __attribute__((ext_vector_type(8))) short bf16x8;
typedef __attribute__((ext_vector_type(4))) float f32x4;
typedef __attribute__((ext_vector_type(4))) unsigned short us4;

// ---- problem dims ----
#define NBAT 8
#define NN   1024
#define DRNN 128
#define DIN  64
#define TT   32

// ---- workspace layout (bytes) ----
#define FLAGS_OFF 0                       // 256 flags * 64B stride = 16 KB
#define OBS_OFF   (16*1024)               // 256 floats
#define XCD_OFF   (20*1024)               // 256 ints (XCD id per wg)
#define WT_OFF    (32*1024)               // 131072 bf16 = 256 KB
#define TB_OFF    (512*1024)
#define TBHALF    (NBAT*256*1024)         // elements per t ping-pong buffer (bf16)

// transposed-weight element offsets inside wtb (bf16)
#define W0T_E   0
#define W1T_E   16384
#define WOUTT_E 32768
#define WZRT_E  49152        // [256][192]
#define WHT_E   98304        // [128][192]
#define WOT_E   122880       // [64][128]
#define WT_TOTAL 131072

// ---- LDS layout ----
#define ALDS_STRIDE 1032                  // 1024 + 8 pad (shorts)
#define XH_OFF_S   (32*ALDS_STRIDE)       // 33024 shorts
#define XH_STRIDE  200                    // up to K=192 + 8 pad
#define ST_OFF_S   (XH_OFF_S + 32*XH_STRIDE)   // state floats after this
#define SROW 132                          // 128 + 4 pad (floats) -> 2-way max (free)
#define LDS_BYTES  (ST_OFF_S*2 + 3*32*SROW*4)  // 129536 B

static_assert(LDS_BYTES <= 160*1024, "LDS overflow");

DEVINL float b2f(short s) {
    union { unsigned u; float f; } x;
    x.u = ((unsigned)(unsigned short)s) << 16;
    return x.f;
}
DEVINL unsigned short f2b(float f) {
    union { unsigned u; float f; } x;
    x.f = f;
    unsigned u = x.u;
    u += 0x7fffu + ((u >> 16) & 1u);      // RNE
    return (unsigned short)(u >> 16);
}
DEVINL float sigm(float x) { return __builtin_amdgcn_rcpf(1.f + __expf(-x)); }
DEVINL float tanh_fast(float x) {
    float e = __expf(-2.f * fabsf(x));
    float r = (1.f - e) * __builtin_amdgcn_rcpf(1.f + e);
    return copysignf(r, x);
}

// ---- barriers ----
// bar_local: all 32 peer wgs verified on SAME XCD (shared L2). Data stores
// drained to L2 (vmcnt 0) before flag store; flag store/poll via sc0 ops
// (L1-bypass, L2-hit, ~200cy instead of ~900cy MALL round-trip). Readers
// invalidate L1 only.
DEVINL void bar_local(int* flags, int b, int wg, int r) {
    asm volatile("s_waitcnt vmcnt(0)" ::: "memory");
    __syncthreads();
    if (threadIdx.x == 0) {
        int* p = &flags[(b*32 + wg)*16];
        asm volatile("global_store_dword %0, %1, off sc0" :: "v"(p), "v"(r) : "memory");
    }
    if (threadIdx.x < 32) {
        const int* f = &flags[(b*32 + (int)threadIdx.x)*16];
        int v;
        for (;;) {
            asm volatile("global_load_dword %0, %1, off sc0\n\ts_waitcnt vmcnt(0)"
                         : "=v"(v) : "v"(f) : "memory");
            if (v >= r) break;
        }
    }
    __syncthreads();
    asm volatile("buffer_inv sc0" ::: "memory");   // L1-only invalidate
}

// bar_global: cross-XCD correct (agent fences + agent-scope atomics).
DEVINL void bar_global(int* flags, int b, int wg, int r) {
    __syncthreads();
    if (threadIdx.x == 0) {
        __threadfence();
        __hip_atomic_store(&flags[(b*32 + wg)*16], r, __ATOMIC_RELEASE, __HIP_MEMORY_SCOPE_AGENT);
    }
    if (threadIdx.x < 64) {
        if (threadIdx.x < 32) {
            int* f = &flags[(b*32 + (int)threadIdx.x)*16];
            while (__hip_atomic_load(f, __ATOMIC_RELAXED, __HIP_MEMORY_SCOPE_AGENT) < r)
                __builtin_amdgcn_s_sleep(2);
        }
        __threadfence();
    }
    __syncthreads();
}

// ---- main matmul: S[32 x 16*NB*4waves] = A_lds[32x1024] @ tT ----
template<int NB, int PF>
DEVINL void mmul(const short* Alds, const short* __restrict__ Tb,
                 int lane, int wv, f32x4 (&acc)[2][NB]) {
    const int q = lane >> 4, mr = lane & 15;
    const short* a0p = Alds + mr*ALDS_STRIDE + q*8;
    const short* a1p = Alds + (16+mr)*ALDS_STRIDE + q*8;
    const short* bp[NB];
#pragma unroll
    for (int n = 0; n < NB; n++) bp[n] = Tb + (wv*(16*NB) + n*16 + mr)*NN + q*8;
    bf16x8 ab[PF][2]; bf16x8 bb[PF][NB];
#pragma unroll
    for (int p = 0; p < PF; p++) {
        ab[p][0] = *(const bf16x8*)(a0p + p*32);
        ab[p][1] = *(const bf16x8*)(a1p + p*32);
#pragma unroll
        for (int n = 0; n < NB; n++) bb[p][n] = *(const bf16x8*)(bp[n] + p*32);
    }
#pragma unroll 1
    for (int kb = 0; kb < 32 - PF; kb += PF) {
#pragma unroll
        for (int p = 0; p < PF; p++) {
#pragma unroll
            for (int m = 0; m < 2; m++)
#pragma unroll
                for (int n = 0; n < NB; n++)
                    acc[m][n] = __builtin_amdgcn_mfma_f32_16x16x32_bf16(ab[p][m], bb[p][n], acc[m][n], 0, 0, 0);
            const int ko = (kb + PF + p)*32;
            ab[p][0] = *(const bf16x8*)(a0p + ko);
            ab[p][1] = *(const bf16x8*)(a1p + ko);
#pragma unroll
            for (int n = 0; n < NB; n++) bb[p][n] = *(const bf16x8*)(bp[n] + ko);
        }
    }
#pragma unroll
    for (int p = 0; p < PF; p++)
#pragma unroll
        for (int m = 0; m < 2; m++)
#pragma unroll
            for (int n = 0; n < NB; n++)
                acc[m][n] = __builtin_amdgcn_mfma_f32_16x16x32_bf16(ab[p][m], bb[p][n], acc[m][n], 0, 0, 0);
}

// ---- epilogue small matmul: out[32 x DOUT] = xh[32 x K] @ W (W transposed,
// streamed per-lane from global/L2). Caller syncs after xh writes.
template<int K, int DOUT, typename WR>
DEVINL void smm(const short* __restrict__ WTg, int xoff, int wv, int q, int mr,
                const short* xh, WR&& wr) {
    constexpr int CH = DOUT / 64;
#pragma unroll
    for (int ch = 0; ch < CH; ch++) {
        f32x4 o[2];
        o[0] = f32x4{0.f,0.f,0.f,0.f}; o[1] = f32x4{0.f,0.f,0.f,0.f};
        const short* wrow = WTg + (ch*64 + wv*16 + mr)*K + q*8;
#pragma unroll
        for (int ks = 0; ks < K/32; ks++) {
            bf16x8 bw = *(const bf16x8*)(wrow + ks*32);
            bf16x8 a0 = *(const bf16x8*)(xh + mr*XH_STRIDE + xoff + ks*32 + q*8);
            bf16x8 a1 = *(const bf16x8*)(xh + (16+mr)*XH_STRIDE + xoff + ks*32 + q*8);
            o[0] = __builtin_amdgcn_mfma_f32_16x16x32_bf16(a0, bw, o[0], 0, 0, 0);
            o[1] = __builtin_amdgcn_mfma_f32_16x16x32_bf16(a1, bw, o[1], 0, 0, 0);
        }
        wr(ch, o);
    }
}

// ---- prep: transpose+convert all weights (fp32 -> bf16) into ws ----
__global__ void prep_wt(const float* __restrict__ W0, const float* __restrict__ W1,
                        const float* __restrict__ Wout, const float* __restrict__ Wz,
                        const float* __restrict__ Wr, const float* __restrict__ Wh,
                        const float* __restrict__ Wo, short* __restrict__ wtb) {
    int i = blockIdx.x*256 + threadIdx.x;
    if (i >= WT_TOTAL) return;
    float v;
    if (i < 16384)       { int c = i >> 7, k = i & 127; v = W0[k*128 + c]; }
    else if (i < 32768)  { int j = i - 16384;  int c = j >> 7, k = j & 127; v = W1[k*128 + c]; }
    else if (i < 49152)  { int j = i - 32768;  int c = j >> 7, k = j & 127; v = Wout[k*128 + c]; }
    else if (i < 98304)  { int j = i - 49152;  int c = j / 192, k = j % 192;
                           v = (c < 128) ? Wz[k*128 + c] : Wr[k*128 + (c - 128)]; }
    else if (i < 122880) { int j = i - 98304;  int c = j / 192, k = j % 192; v = Wh[k*128 + c]; }
    else                 { int j = i - 122880; int c = j >> 7, k = j & 127; v = Wo[k*64 + c]; }
    wtb[i] = (short)f2b(v);
}

// ---- prep: obs[b][t] = (sum |mask| > 1e-4) ----
__global__ void prep_obs(const float* __restrict__ msk, float* __restrict__ obs) {
    int blk = blockIdx.x;   // b*32 + t
    const float* p = msk + (size_t)blk*65536;
    float s = 0.f;
    for (int it = 0; it < 64; ++it) {
        f32x4 v = *(const f32x4*)(p + it*1024 + threadIdx.x*4);
        s += fabsf(v[0]) + fabsf(v[1]) + fabsf(v[2]) + fabsf(v[3]);
    }
#pragma unroll
    for (int off = 32; off; off >>= 1) s += __shfl_down(s, off, 64);
    __shared__ float red[4];
    if ((threadIdx.x & 63) == 0) red[threadIdx.x >> 6] = s;
    __syncthreads();
    if (threadIdx.x == 0) {
        float tot = red[0] + red[1] + red[2] + red[3];
        obs[blk] = (tot > 1e-4f) ? 1.f : 0.f;
    }
}

// ---- the persistent kernel (single body, data-driven round dispatch) ----
__global__ __launch_bounds__(256, 1) void gcode_persist(
    const float* __restrict__ A, const float* __restrict__ vals, const float* __restrict__ msk,
    const float* __restrict__ h0, const float* __restrict__ b0, const float* __restrict__ b1,
    const float* __restrict__ bout, const float* __restrict__ bz, const float* __restrict__ br,
    const float* __restrict__ bh, const float* __restrict__ bo,
    const short* __restrict__ wtb, short* __restrict__ tb,
    const float* __restrict__ obs, int* flags, int* xcds,
    float* __restrict__ outp)
{
    extern __shared__ short smem[];
    short* Alds = smem;
    short* xh   = smem + XH_OFF_S;
    float* hsL  = (float*)(smem + ST_OFF_S);    // [32][SROW] wg-private state
    float* hv1L = hsL + 32*SROW;
    float* zbL  = hsL + 64*SROW;

    const int tid = threadIdx.x;
    const int wgid = blockIdx.x;
    const int b = wgid & 7, wg = wgid >> 3;
    const int j0 = wg*32;
    const int lane = tid & 63, wv = tid >> 6;
    const int q = lane >> 4, mr = lane & 15;

    // ---- guard phase: is this batch's wg set XCD-local? ----
    int myxcd;
    asm volatile("s_getreg_b32 %0, hwreg(HW_REG_XCC_ID)" : "=s"(myxcd));
    if (tid == 0)
        __hip_atomic_store(&xcds[wgid], myxcd, __ATOMIC_RELAXED, __HIP_MEMORY_SCOPE_AGENT);
    bar_global(flags, b, wg, 1);
    int* scr = (int*)(smem + XH_OFF_S);
    if (tid < 32) {
        int x = __hip_atomic_load(&xcds[b*32 + tid], __ATOMIC_RELAXED, __HIP_MEMORY_SCOPE_AGENT);
        scr[tid] = (x == myxcd) ? 1 : 0;
    }
    __syncthreads();
    int all = 1;
#pragma unroll
    for (int i = 0; i < 32; i++) all &= scr[i];
    __syncthreads();
    const bool local = (all != 0);

    // ---- preload all biases into registers ----
    float b0a, b0b, b1a, b1b, bta, btb, bha, bhb, bzr0, bzr1, bzr2, bzr3, bo_;
    {
        int c0 = wv*32 + mr, c1 = c0 + 16;
        b0a = b0[c0];  b0b = b0[c1];
        b1a = b1[c0];  b1b = b1[c1];
        bta = bout[c0]; btb = bout[c1];
        bha = bh[c0];  bhb = bh[c1];
        int cz = wv*64 + mr;
        bzr0 = (wv < 2) ? bz[cz]      : br[cz - 128];
        bzr1 = (wv < 2) ? bz[cz + 16] : br[cz - 112];
        bzr2 = (wv < 2) ? bz[cz + 32] : br[cz - 96];
        bzr3 = (wv < 2) ? bz[cz + 48] : br[cz - 80];
        bo_  = bo[wv*16 + mr];
    }

    int rd;
    const short* tread;
    short* twrite;
    int cur_t = 0;

    auto lsx = [&](int jl, int c) { return jl*SROW + c; };
    auto wrT = [&](int ch, f32x4 (&o)[2]) {       // next-t write (transposed [c][j]) bf16
        int cp = ch*64 + wv*16 + mr;
        unsigned short* dst = (unsigned short*)twrite + cp*NN + j0 + q*4;
#pragma unroll
        for (int m = 0; m < 2; m++) {
            us4 u;
#pragma unroll
            for (int r = 0; r < 4; r++) u[r] = f2b(o[m][r]);
            *(us4*)(dst + m*16) = u;
        }
    };
    auto wrOut = [&](int ch, f32x4 (&o)[2]) {     // fp32 output projection (DOUT=64)
        (void)ch;
        int cp = wv*16 + mr;
#pragma unroll
        for (int m = 0; m < 2; m++)
#pragma unroll
            for (int r = 0; r < 4; r++) {
                int j = j0 + m*16 + q*4 + r;
                outp[((b*31 + (cur_t - 1))*NN + j)*DIN + cp] = o[m][r] + bo_;
            }
    };
    auto fill_x = [&](int t) {                    // xh[:, 0:64] = bf16(values*masks)
        int j = tid >> 3, c8 = (tid & 7)*8;
        int off = (((b*TT + t)*NN) + j0 + j)*DIN + c8;
        f32x4 v0 = *(const f32x4*)(vals + off);
        f32x4 v1 = *(const f32x4*)(vals + off + 4);
        f32x4 m0 = *(const f32x4*)(msk + off);
        f32x4 m1 = *(const f32x4*)(msk + off + 4);
        bf16x8 r8;
#pragma unroll
        for (int i = 0; i < 4; i++) {
            r8[i]     = (short)f2b(v0[i]*m0[i]);
            r8[4 + i] = (short)f2b(v1[i]*m1[i]);
        }
        *(bf16x8*)(xh + j*XH_STRIDE + c8) = r8;
    };

    // ================= round 0: A slice fp32->bf16 into LDS, init hs and t1 =================
    {
        const float* Ab = A + (size_t)b*NN*NN + (size_t)j0*NN;
        for (int v = tid*4; v < 32*1024; v += 256*4) {
            int row = v >> 10, col = v & 1023;
            f32x4 f = *(const f32x4*)(Ab + row*NN + col);
            us4 u;
#pragma unroll
            for (int i = 0; i < 4; i++) u[i] = f2b(f[i]);
            *(us4*)(Alds + row*ALDS_STRIDE + col) = u;
        }
        int j = tid >> 3, c16 = (tid & 7)*16;
#pragma unroll
        for (int i = 0; i < 16; i++) hsL[lsx(j, c16 + i)] = h0[c16 + i];
        if (tid < 128) {       // t1 row (identical for all j): h0 @ W0
            float a = 0.f;
            const short* w0t = wtb + W0T_E + tid*128;
            for (int d = 0; d < 128; d++) a += h0[d] * b2f(w0t[d]);
            unsigned short bv = f2b(a);
            us4 u = {bv, bv, bv, bv};
            unsigned short* dst = (unsigned short*)(tb) + (b*256 + tid)*NN + j0;
#pragma unroll
            for (int i = 0; i < 8; i++) *(us4*)(dst + i*4) = u;
        }
    }
    rd = 1;
    if (local) bar_local(flags, b, wg, rd + 1); else bar_global(flags, b, wg, rd + 1);

    // ================= data-driven schedule: 161 rounds, one call site each =================
    // r<3: prologue {T(b0,W1), T(b1,Wout), HUP}; r>=3: rr=r-3, t=rr/5,
    // ph = rr%5: {T(b0,W1), T(b1,Wout), R3(t), R4, R5(t)} (last t: first 3 only).
#pragma unroll 1
    for (int r = 0; r < 161; ++r) {
        tread  = tb + ((rd & 1) ^ 1)*TBHALF + b*256*NN;
        twrite = tb + (rd & 1)*TBHALF + b*256*NN;
        int t = 0, ph;
        if (r < 3) ph = (r == 2) ? 5 : r;
        else { int rr = r - 3; t = rr/5; ph = rr - t*5; }

        if (ph == 3) {
            // ---- R4: z -> zbL; r -> t5 = [x | r*hv1]@Wh ----
            f32x4 acc[2][4];
#pragma unroll
            for (int m = 0; m < 2; m++)
#pragma unroll
                for (int n = 0; n < 4; n++) acc[m][n] = f32x4{0.f,0.f,0.f,0.f};
            mmul<4, 4>(Alds, tread, lane, wv, acc);
            float bzr[4] = {bzr0, bzr1, bzr2, bzr3};
            if (wv < 2) {
#pragma unroll
                for (int n = 0; n < 4; n++) {
                    int c = wv*64 + n*16 + mr;
#pragma unroll
                    for (int m = 0; m < 2; m++) {
                        int jl = m*16 + q*4;
#pragma unroll
                        for (int rr2 = 0; rr2 < 4; rr2++)
                            zbL[lsx(jl + rr2, c)] = sigm(acc[m][n][rr2] + bzr[n]);
                    }
                }
            } else {
#pragma unroll
                for (int n = 0; n < 4; n++) {
                    int cr = wv*64 + n*16 + mr - 128;
#pragma unroll
                    for (int m = 0; m < 2; m++) {
                        int jl = m*16 + q*4;
#pragma unroll
                        for (int rr2 = 0; rr2 < 4; rr2++) {
                            int jr = jl + rr2;
                            float rv = sigm(acc[m][n][rr2] + bzr[n]);
                            xh[jr*XH_STRIDE + 64 + cr] = (short)f2b(rv * hv1L[lsx(jr, cr)]);
                        }
                    }
                }
            }
            __syncthreads();
            smm<192, 128>(wtb + WHT_E, 0, wv, q, mr, xh, wrT);
        } else if (ph == 2) {
            // ---- R3: hv1 = hs + DT*(S+bout); t4 = [x|hv1]@[Wz|Wr]; out proj ----
            f32x4 acc[2][2];
#pragma unroll
            for (int m = 0; m < 2; m++) { acc[m][0] = f32x4{0.f,0.f,0.f,0.f}; acc[m][1] = f32x4{0.f,0.f,0.f,0.f}; }
            mmul<2, 8>(Alds, tread, lane, wv, acc);
            fill_x(t);
            float bb2[2] = {bta, btb};
#pragma unroll
            for (int n = 0; n < 2; n++) {
                int c = wv*32 + n*16 + mr;
#pragma unroll
                for (int m = 0; m < 2; m++) {
                    int jl = m*16 + q*4;
#pragma unroll
                    for (int rr2 = 0; rr2 < 4; rr2++) {
                        int jr = jl + rr2;
                        float hv = hsL[lsx(jr, c)] + 0.25f*(acc[m][n][rr2] + bb2[n]);
                        hv1L[lsx(jr, c)] = hv;
                        xh[jr*XH_STRIDE + 64 + c] = (short)f2b(hv);
                    }
                }
            }
            __syncthreads();
            smm<192, 256>(wtb + WZRT_E, 0, wv, q, mr, xh, wrT);
            if (t >= 1) {
                cur_t = t;
                smm<128, 64>(wtb + WOT_E, 64, wv, q, mr, xh, wrOut);
            }
        } else {
            // ---- roundA: kinds 0,1 = tanh(.+b)@W; 2 = HUP; 3 = R5/GRU-h ----
            int kind = (ph == 5) ? 2 : (ph == 4) ? 3 : ph;
            float ob = 0.f;
            if (kind == 3) ob = obs[b*TT + t];
            const short* WT = wtb + ((kind == 0) ? W1T_E : (kind == 1) ? WOUTT_E : W0T_E);
            float bn0 = (kind == 0) ? b0a : (kind == 1) ? b1a : (kind == 2) ? bta : bha;
            float bn1 = (kind == 0) ? b0b : (kind == 1) ? b1b : (kind == 2) ? btb : bhb;
            f32x4 acc[2][2];
#pragma unroll
            for (int m = 0; m < 2; m++) { acc[m][0] = f32x4{0.f,0.f,0.f,0.f}; acc[m][1] = f32x4{0.f,0.f,0.f,0.f}; }
            mmul<2, 8>(Alds, tread, lane, wv, acc);
            float bn[2] = {bn0, bn1};
#pragma unroll
            for (int n = 0; n < 2; n++) {
                int c = wv*32 + n*16 + mr;
#pragma unroll
                for (int m = 0; m < 2; m++) {
                    int jl = m*16 + q*4;
#pragma unroll
                    for (int rr2 = 0; rr2 < 4; rr2++) {
                        int jr = jl + rr2;
                        float s = acc[m][n][rr2] + bn[n];
                        float xv;
                        if (kind <= 1) {
                            xv = tanh_fast(s);
                        } else if (kind == 2) {
                            xv = hsL[lsx(jr, c)] + 0.25f*s;
                            hsL[lsx(jr, c)] = xv;
                        } else {
                            float cc = tanh_fast(s);
                            float hvv = hv1L[lsx(jr, c)];
                            xv = hvv + ob*zbL[lsx(jr, c)]*(cc - hvv);
                            hsL[lsx(jr, c)] = xv;
                        }
                        xh[jr*XH_STRIDE + c] = (short)f2b(xv);
                    }
                }
            }
            __syncthreads();
            smm<128, 128>(WT, 0, wv, q, mr, xh, wrT);
        }

        rd++;
        if (local) bar_local(flags, b, wg, rd + 1); else bar_global(flags, b, wg, rd + 1);
    }
}

extern "C" void kernel_launch(void* const* d_in, const int* in_sizes, int n_in,
                              void* d_out, int out_size, void* d_ws, size_t ws_size,
                              hipStream_t stream) {
    (void)in_sizes; (void)n_in; (void)out_size; (void)ws_size;
    const float* vals = (const float*)d_in[0];
    const float* msk  = (const float*)d_in[1];
    const float* A    = (const float*)d_in[2];
    const float* h0   = (const float*)d_in[3];
    const float* W0   = (const float*)d_in[4];
    const float* b0   = (const float*)d_in[5];
    const float* W1   = (const float*)d_in[6];
    const float* b1   = (const float*)d_in[7];
    const float* Wout = (const float*)d_in[8];
    const float* bout = (const float*)d_in[9];
    const float* Wz   = (const float*)d_in[10];
    const float* bz   = (const float*)d_in[11];
    const float* Wr   = (const float*)d_in[12];
    const float* br   = (const float*)d_in[13];
    const float* Wh   = (const float*)d_in[14];
    const float* bh   = (const float*)d_in[15];
    const float* Wo   = (const float*)d_in[16];
    const float* bo   = (const float*)d_in[17];

    char* ws = (char*)d_ws;
    int*   flags = (int*)(ws + FLAGS_OFF);
    float* obs   = (float*)(ws + OBS_OFF);
    int*   xcds  = (int*)(ws + XCD_OFF);
    short* wtb   = (short*)(ws + WT_OFF);
    short* tb    = (short*)(ws + TB_OFF);

    hipMemsetAsync(flags, 0, 16*1024, stream);
    prep_wt<<<(WT_TOTAL + 255)/256, 256, 0, stream>>>(W0, W1, Wout, Wz, Wr, Wh, Wo, wtb);
    prep_obs<<<NBAT*TT, 256, 0, stream>>>(msk, obs);

    hipFuncSetAttribute((const void*)gcode_persist,
                        hipFuncAttributeMaxDynamicSharedMemorySize, LDS_BYTES);
    gcode_persist<<<256, 256, LDS_BYTES, stream>>>(
        A, vals, msk, h0, b0, b1, bout, bz, br, bh, bo,
        wtb, tb, obs, flags, xcds, (float*)d_out);
}

// Round 5
// 2354.881 us; speedup vs baseline: 1.9704x; 1.9704x over previous
//
#include <hip/hip_runtime.h>
#include <stdint.h>

#define DEVINL __device__ __forceinline__

typedef __attribute__((ext_vector_type(8))) short bf16x8;
typedef __attribute__((ext_vector_type(4))) float f32x4;
typedef __attribute__((ext_vector_type(4))) unsigned short us4;

// ---- problem dims ----
#define NBAT 8
#define NN   1024
#define DRNN 128
#define DIN  64
#define TT   32

// ---- workspace layout (bytes) ----
#define FLAGS_OFF 0                       // 256 round-flags * 64B stride = 16 KB
#define SFLG_OFF  (16*1024)               // 256 setup-flags * 64B = 16 KB (disjoint lines)
#define OBS_OFF   (32*1024)               // 256 floats
#define XCD_OFF   (36*1024)               // 8 per-XCD rank counters
#define WT_OFF    (64*1024)               // 131072 bf16 = 256 KB
#define TB_OFF    (512*1024)
#define TBHALF    (NBAT*256*1024)         // elements per t ping-pong buffer (bf16)

// transposed-weight element offsets inside wtb (bf16)
#define W0T_E   0
#define W1T_E   16384
#define WOUTT_E 32768
#define WZRT_E  49152        // [256][192]
#define WHT_E   98304        // [128][192]
#define WOT_E   122880       // [64][128]
#define WT_TOTAL 131072

// ---- LDS layout ----
#define ALDS_STRIDE 1032                  // 1024 + 8 pad (shorts)
#define XH_OFF_S   (32*ALDS_STRIDE)       // 33024 shorts
#define XH_STRIDE  200                    // up to K=192 + 8 pad
#define ST_OFF_S   (XH_OFF_S + 32*XH_STRIDE)   // state floats after this
#define SROW 132                          // 128 + 4 pad (floats) -> 2-way max (free)
#define LDS_BYTES  (ST_OFF_S*2 + 3*32*SROW*4)  // 129536 B

static_assert(LDS_BYTES <= 160*1024, "LDS overflow");

DEVINL float b2f(short s) {
    union { unsigned u; float f; } x;
    x.u = ((unsigned)(unsigned short)s) << 16;
    return x.f;
}
DEVINL unsigned short f2b(float f) {
    union { unsigned u; float f; } x;
    x.f = f;
    unsigned u = x.u;
    u += 0x7fffu + ((u >> 16) & 1u);      // RNE
    return (unsigned short)(u >> 16);
}
DEVINL float sigm(float x) { return __builtin_amdgcn_rcpf(1.f + __expf(-x)); }
DEVINL float tanh_fast(float x) {
    float e = __expf(-2.f * fabsf(x));
    float r = (1.f - e) * __builtin_amdgcn_rcpf(1.f + e);
    return copysignf(r, x);
}

// ---- barriers ----
// bar_local: all 32 peer wgs GUARANTEED on the same XCD (self-organized by
// XCC_ID; validated bijection). Ordering: every thread drains its own vmem
// (vmcnt 0) -> data is physically in the shared XCD L2 BEFORE the flag
// store issues. Flag store/poll = relaxed AGENT-scope atomics (visibility
// proven by R0-R2's working barrier polls; relaxed => NO buffer_wbl2, the
// L2 is never flushed). Readers then invalidate L1 only (buffer_inv sc0)
// so normal loads refill from the shared, still-hot L2.
DEVINL void bar_local(int* flags, int b, int wg, int r) {
    asm volatile("s_waitcnt vmcnt(0)" ::: "memory");
    __syncthreads();
    if (threadIdx.x == 0)
        __hip_atomic_store(&flags[(b*32 + wg)*16], r, __ATOMIC_RELAXED, __HIP_MEMORY_SCOPE_AGENT);
    if (threadIdx.x < 32) {
        int* f = &flags[(b*32 + (int)threadIdx.x)*16];
        while (__hip_atomic_load(f, __ATOMIC_RELAXED, __HIP_MEMORY_SCOPE_AGENT) < r)
            __builtin_amdgcn_s_sleep(1);
    }
    __syncthreads();
    asm volatile("buffer_inv sc0" ::: "memory");   // L1-only invalidate
}

// bar_global: cross-XCD correct (agent fences + agent-scope atomics).
DEVINL void bar_global(int* flags, int b, int wg, int r) {
    __syncthreads();
    if (threadIdx.x == 0) {
        __threadfence();
        __hip_atomic_store(&flags[(b*32 + wg)*16], r, __ATOMIC_RELEASE, __HIP_MEMORY_SCOPE_AGENT);
    }
    if (threadIdx.x < 64) {
        if (threadIdx.x < 32) {
            int* f = &flags[(b*32 + (int)threadIdx.x)*16];
            while (__hip_atomic_load(f, __ATOMIC_RELAXED, __HIP_MEMORY_SCOPE_AGENT) < r)
                __builtin_amdgcn_s_sleep(2);
        }
        __threadfence();
    }
    __syncthreads();
}

// ---- main matmul: S[32 x 16*NB*4waves] = A_lds[32x1024] @ tT ----
template<int NB, int PF>
DEVINL void mmul(const short* Alds, const short* __restrict__ Tb,
                 int lane, int wv, f32x4 (&acc)[2][NB]) {
    const int q = lane >> 4, mr = lane & 15;
    const short* a0p = Alds + mr*ALDS_STRIDE + q*8;
    const short* a1p = Alds + (16+mr)*ALDS_STRIDE + q*8;
    const short* bp[NB];
#pragma unroll
    for (int n = 0; n < NB; n++) bp[n] = Tb + (wv*(16*NB) + n*16 + mr)*NN + q*8;
    bf16x8 ab[PF][2]; bf16x8 bb[PF][NB];
#pragma unroll
    for (int p = 0; p < PF; p++) {
        ab[p][0] = *(const bf16x8*)(a0p + p*32);
        ab[p][1] = *(const bf16x8*)(a1p + p*32);
#pragma unroll
        for (int n = 0; n < NB; n++) bb[p][n] = *(const bf16x8*)(bp[n] + p*32);
    }
#pragma unroll 1
    for (int kb = 0; kb < 32 - PF; kb += PF) {
#pragma unroll
        for (int p = 0; p < PF; p++) {
#pragma unroll
            for (int m = 0; m < 2; m++)
#pragma unroll
                for (int n = 0; n < NB; n++)
                    acc[m][n] = __builtin_amdgcn_mfma_f32_16x16x32_bf16(ab[p][m], bb[p][n], acc[m][n], 0, 0, 0);
            const int ko = (kb + PF + p)*32;
            ab[p][0] = *(const bf16x8*)(a0p + ko);
            ab[p][1] = *(const bf16x8*)(a1p + ko);
#pragma unroll
            for (int n = 0; n < NB; n++) bb[p][n] = *(const bf16x8*)(bp[n] + ko);
        }
    }
#pragma unroll
    for (int p = 0; p < PF; p++)
#pragma unroll
        for (int m = 0; m < 2; m++)
#pragma unroll
            for (int n = 0; n < NB; n++)
                acc[m][n] = __builtin_amdgcn_mfma_f32_16x16x32_bf16(ab[p][m], bb[p][n], acc[m][n], 0, 0, 0);
}

// ---- epilogue small matmul: out[32 x DOUT] = xh[32 x K] @ W (W transposed,
// streamed per-lane from global/L2). Caller syncs after xh writes.
template<int K, int DOUT, typename WR>
DEVINL void smm(const short* __restrict__ WTg, int xoff, int wv, int q, int mr,
                const short* xh, WR&& wr) {
    constexpr int CH = DOUT / 64;
#pragma unroll
    for (int ch = 0; ch < CH; ch++) {
        f32x4 o[2];
        o[0] = f32x4{0.f,0.f,0.f,0.f}; o[1] = f32x4{0.f,0.f,0.f,0.f};
        const short* wrow = WTg + (ch*64 + wv*16 + mr)*K + q*8;
#pragma unroll
        for (int ks = 0; ks < K/32; ks++) {
            bf16x8 bw = *(const bf16x8*)(wrow + ks*32);
            bf16x8 a0 = *(const bf16x8*)(xh + mr*XH_STRIDE + xoff + ks*32 + q*8);
            bf16x8 a1 = *(const bf16x8*)(xh + (16+mr)*XH_STRIDE + xoff + ks*32 + q*8);
            o[0] = __builtin_amdgcn_mfma_f32_16x16x32_bf16(a0, bw, o[0], 0, 0, 0);
            o[1] = __builtin_amdgcn_mfma_f32_16x16x32_bf16(a1, bw, o[1], 0, 0, 0);
        }
        wr(ch, o);
    }
}

// ---- prep: transpose+convert all weights (fp32 -> bf16) into ws ----
__global__ void prep_wt(const float* __restrict__ W0, const float* __restrict__ W1,
                        const float* __restrict__ Wout, const float* __restrict__ Wz,
                        const float* __restrict__ Wr, const float* __restrict__ Wh,
                        const float* __restrict__ Wo, short* __restrict__ wtb) {
    int i = blockIdx.x*256 + threadIdx.x;
    if (i >= WT_TOTAL) return;
    float v;
    if (i < 16384)       { int c = i >> 7, k = i & 127; v = W0[k*128 + c]; }
    else if (i < 32768)  { int j = i - 16384;  int c = j >> 7, k = j & 127; v = W1[k*128 + c]; }
    else if (i < 49152)  { int j = i - 32768;  int c = j >> 7, k = j & 127; v = Wout[k*128 + c]; }
    else if (i < 98304)  { int j = i - 49152;  int c = j / 192, k = j % 192;
                           v = (c < 128) ? Wz[k*128 + c] : Wr[k*128 + (c - 128)]; }
    else if (i < 122880) { int j = i - 98304;  int c = j / 192, k = j % 192; v = Wh[k*128 + c]; }
    else                 { int j = i - 122880; int c = j >> 7, k = j & 127; v = Wo[k*64 + c]; }
    wtb[i] = (short)f2b(v);
}

// ---- prep: obs[b][t] = (sum |mask| > 1e-4) ----
__global__ void prep_obs(const float* __restrict__ msk, float* __restrict__ obs) {
    int blk = blockIdx.x;   // b*32 + t
    const float* p = msk + (size_t)blk*65536;
    float s = 0.f;
    for (int it = 0; it < 64; ++it) {
        f32x4 v = *(const f32x4*)(p + it*1024 + threadIdx.x*4);
        s += fabsf(v[0]) + fabsf(v[1]) + fabsf(v[2]) + fabsf(v[3]);
    }
#pragma unroll
    for (int off = 32; off; off >>= 1) s += __shfl_down(s, off, 64);
    __shared__ float red[4];
    if ((threadIdx.x & 63) == 0) red[threadIdx.x >> 6] = s;
    __syncthreads();
    if (threadIdx.x == 0) {
        float tot = red[0] + red[1] + red[2] + red[3];
        obs[blk] = (tot > 1e-4f) ? 1.f : 0.f;
    }
}

// ---- the persistent kernel (XCD-self-organizing batch assignment) ----
__global__ __launch_bounds__(256, 1) void gcode_persist(
    const float* __restrict__ A, const float* __restrict__ vals, const float* __restrict__ msk,
    const float* __restrict__ h0, const float* __restrict__ b0, const float* __restrict__ b1,
    const float* __restrict__ bout, const float* __restrict__ bz, const float* __restrict__ br,
    const float* __restrict__ bh, const float* __restrict__ bo,
    const short* __restrict__ wtb, short* __restrict__ tb,
    const float* __restrict__ obs, int* flags, int* cnt,
    float* __restrict__ outp)
{
    extern __shared__ short smem[];
    short* Alds = smem;
    short* xh   = smem + XH_OFF_S;
    float* hsL  = (float*)(smem + ST_OFF_S);    // [32][SROW] wg-private state
    float* hv1L = hsL + 32*SROW;
    float* zbL  = hsL + 64*SROW;

    const int tid = threadIdx.x;
    const int wgid = blockIdx.x;
    const int lane = tid & 63, wv = tid >> 6;
    const int q = lane >> 4, mr = lane & 15;
    int* scr = (int*)(smem + XH_OFF_S);
    int* sflg = flags + 4096;                    // setup flags (disjoint 16 KB)

    // ---- setup: discover XCD, claim a rank on it, validate the partition ----
    // LDS cap forces 1 wg/CU, grid==CU count => bijection => 32 wgs/XCD.
    int myxcd;
    asm volatile("s_getreg_b32 %0, hwreg(HW_REG_XCC_ID)" : "=s"(myxcd));
    myxcd &= 15;
    if (tid == 0) {
        int r = (myxcd < 8)
            ? __hip_atomic_fetch_add(&cnt[myxcd], 1, __ATOMIC_RELAXED, __HIP_MEMORY_SCOPE_AGENT)
            : 999;
        scr[0] = r;
    }
    __syncthreads();
    const int rank = scr[0];
    __syncthreads();
    // full-grid barrier (agent scope); co-residency proven by R0-R2's
    // per-batch spin barriers on the same 256-wg persistent launch.
    if (tid == 0) {
        __threadfence();
        __hip_atomic_store(&sflg[wgid*16], 1, __ATOMIC_RELEASE, __HIP_MEMORY_SCOPE_AGENT);
    }
    {
        int* f = &sflg[tid*16];
        while (__hip_atomic_load(f, __ATOMIC_RELAXED, __HIP_MEMORY_SCOPE_AGENT) < 1)
            __builtin_amdgcn_s_sleep(2);
    }
    __threadfence();
    __syncthreads();
    int ok = (myxcd < 8 && rank < 32) ? 1 : 0;
#pragma unroll
    for (int x = 0; x < 8; x++)
        ok &= (__hip_atomic_load(&cnt[x], __ATOMIC_RELAXED, __HIP_MEMORY_SCOPE_AGENT) == 32) ? 1 : 0;
    const bool local = (ok != 0);      // uniform across grid (global property)
    const int b  = local ? myxcd : (wgid & 7);
    const int wg = local ? rank  : (wgid >> 3);
    const int j0 = wg*32;

    // ---- preload all biases into registers ----
    float b0a, b0b, b1a, b1b, bta, btb, bha, bhb, bzr0, bzr1, bzr2, bzr3, bo_;
    {
        int c0 = wv*32 + mr, c1 = c0 + 16;
        b0a = b0[c0];  b0b = b0[c1];
        b1a = b1[c0];  b1b = b1[c1];
        bta = bout[c0]; btb = bout[c1];
        bha = bh[c0];  bhb = bh[c1];
        int cz = wv*64 + mr;
        bzr0 = (wv < 2) ? bz[cz]      : br[cz - 128];
        bzr1 = (wv < 2) ? bz[cz + 16] : br[cz - 112];
        bzr2 = (wv < 2) ? bz[cz + 32] : br[cz - 96];
        bzr3 = (wv < 2) ? bz[cz + 48] : br[cz - 80];
        bo_  = bo[wv*16 + mr];
    }

    int rd;
    const short* tread;
    short* twrite;
    int cur_t = 0;

    auto lsx = [&](int jl, int c) { return jl*SROW + c; };
    auto wrT = [&](int ch, f32x4 (&o)[2]) {       // next-t write (transposed [c][j]) bf16
        int cp = ch*64 + wv*16 + mr;
        unsigned short* dst = (unsigned short*)twrite + cp*NN + j0 + q*4;
#pragma unroll
        for (int m = 0; m < 2; m++) {
            us4 u;
#pragma unroll
            for (int r = 0; r < 4; r++) u[r] = f2b(o[m][r]);
            *(us4*)(dst + m*16) = u;
        }
    };
    auto wrOut = [&](int ch, f32x4 (&o)[2]) {     // fp32 output projection (DOUT=64)
        (void)ch;
        int cp = wv*16 + mr;
#pragma unroll
        for (int m = 0; m < 2; m++)
#pragma unroll
            for (int r = 0; r < 4; r++) {
                int j = j0 + m*16 + q*4 + r;
                outp[((b*31 + (cur_t - 1))*NN + j)*DIN + cp] = o[m][r] + bo_;
            }
    };
    auto fill_x = [&](int t) {                    // xh[:, 0:64] = bf16(values*masks)
        int j = tid >> 3, c8 = (tid & 7)*8;
        int off = (((b*TT + t)*NN) + j0 + j)*DIN + c8;
        f32x4 v0 = *(const f32x4*)(vals + off);
        f32x4 v1 = *(const f32x4*)(vals + off + 4);
        f32x4 m0 = *(const f32x4*)(msk + off);
        f32x4 m1 = *(const f32x4*)(msk + off + 4);
        bf16x8 r8;
#pragma unroll
        for (int i = 0; i < 4; i++) {
            r8[i]     = (short)f2b(v0[i]*m0[i]);
            r8[4 + i] = (short)f2b(v1[i]*m1[i]);
        }
        *(bf16x8*)(xh + j*XH_STRIDE + c8) = r8;
    };

    // ================= round 0: A slice fp32->bf16 into LDS, init hs and t1 =================
    {
        const float* Ab = A + (size_t)b*NN*NN + (size_t)j0*NN;
        for (int v = tid*4; v < 32*1024; v += 256*4) {
            int row = v >> 10, col = v & 1023;
            f32x4 f = *(const f32x4*)(Ab + row*NN + col);
            us4 u;
#pragma unroll
            for (int i = 0; i < 4; i++) u[i] = f2b(f[i]);
            *(us4*)(Alds + row*ALDS_STRIDE + col) = u;
        }
        int j = tid >> 3, c16 = (tid & 7)*16;
#pragma unroll
        for (int i = 0; i < 16; i++) hsL[lsx(j, c16 + i)] = h0[c16 + i];
        if (tid < 128) {       // t1 row (identical for all j): h0 @ W0
            float a = 0.f;
            const short* w0t = wtb + W0T_E + tid*128;
            for (int d = 0; d < 128; d++) a += h0[d] * b2f(w0t[d]);
            unsigned short bv = f2b(a);
            us4 u = {bv, bv, bv, bv};
            unsigned short* dst = (unsigned short*)(tb) + (b*256 + tid)*NN + j0;
#pragma unroll
            for (int i = 0; i < 8; i++) *(us4*)(dst + i*4) = u;
        }
    }
    rd = 1;
    if (local) bar_local(flags, b, wg, rd + 1); else bar_global(flags, b, wg, rd + 1);

    // ================= data-driven schedule: 161 rounds, one call site each =================
    // r<3: prologue {T(b0,W1), T(b1,Wout), HUP}; r>=3: rr=r-3, t=rr/5,
    // ph = rr%5: {T(b0,W1), T(b1,Wout), R3(t), R4, R5(t)} (last t: first 3 only).
#pragma unroll 1
    for (int r = 0; r < 161; ++r) {
        tread  = tb + ((rd & 1) ^ 1)*TBHALF + b*256*NN;
        twrite = tb + (rd & 1)*TBHALF + b*256*NN;
        int t = 0, ph;
        if (r < 3) ph = (r == 2) ? 5 : r;
        else { int rr = r - 3; t = rr/5; ph = rr - t*5; }

        if (ph == 3) {
            // ---- R4: z -> zbL; r -> t5 = [x | r*hv1]@Wh ----
            f32x4 acc[2][4];
#pragma unroll
            for (int m = 0; m < 2; m++)
#pragma unroll
                for (int n = 0; n < 4; n++) acc[m][n] = f32x4{0.f,0.f,0.f,0.f};
            mmul<4, 4>(Alds, tread, lane, wv, acc);
            float bzr[4] = {bzr0, bzr1, bzr2, bzr3};
            if (wv < 2) {
#pragma unroll
                for (int n = 0; n < 4; n++) {
                    int c = wv*64 + n*16 + mr;
#pragma unroll
                    for (int m = 0; m < 2; m++) {
                        int jl = m*16 + q*4;
#pragma unroll
                        for (int rr2 = 0; rr2 < 4; rr2++)
                            zbL[lsx(jl + rr2, c)] = sigm(acc[m][n][rr2] + bzr[n]);
                    }
                }
            } else {
#pragma unroll
                for (int n = 0; n < 4; n++) {
                    int cr = wv*64 + n*16 + mr - 128;
#pragma unroll
                    for (int m = 0; m < 2; m++) {
                        int jl = m*16 + q*4;
#pragma unroll
                        for (int rr2 = 0; rr2 < 4; rr2++) {
                            int jr = jl + rr2;
                            float rv = sigm(acc[m][n][rr2] + bzr[n]);
                            xh[jr*XH_STRIDE + 64 + cr] = (short)f2b(rv * hv1L[lsx(jr, cr)]);
                        }
                    }
                }
            }
            __syncthreads();
            smm<192, 128>(wtb + WHT_E, 0, wv, q, mr, xh, wrT);
        } else if (ph == 2) {
            // ---- R3: hv1 = hs + DT*(S+bout); t4 = [x|hv1]@[Wz|Wr]; out proj ----
            f32x4 acc[2][2];
#pragma unroll
            for (int m = 0; m < 2; m++) { acc[m][0] = f32x4{0.f,0.f,0.f,0.f}; acc[m][1] = f32x4{0.f,0.f,0.f,0.f}; }
            mmul<2, 8>(Alds, tread, lane, wv, acc);
            fill_x(t);
            float bb2[2] = {bta, btb};
#pragma unroll
            for (int n = 0; n < 2; n++) {
                int c = wv*32 + n*16 + mr;
#pragma unroll
                for (int m = 0; m < 2; m++) {
                    int jl = m*16 + q*4;
#pragma unroll
                    for (int rr2 = 0; rr2 < 4; rr2++) {
                        int jr = jl + rr2;
                        float hv = hsL[lsx(jr, c)] + 0.25f*(acc[m][n][rr2] + bb2[n]);
                        hv1L[lsx(jr, c)] = hv;
                        xh[jr*XH_STRIDE + 64 + c] = (short)f2b(hv);
                    }
                }
            }
            __syncthreads();
            smm<192, 256>(wtb + WZRT_E, 0, wv, q, mr, xh, wrT);
            if (t >= 1) {
                cur_t = t;
                smm<128, 64>(wtb + WOT_E, 64, wv, q, mr, xh, wrOut);
            }
        } else {
            // ---- roundA: kinds 0,1 = tanh(.+b)@W; 2 = HUP; 3 = R5/GRU-h ----
            int kind = (ph == 5) ? 2 : (ph == 4) ? 3 : ph;
            float ob = 0.f;
            if (kind == 3) ob = obs[b*TT + t];
            const short* WT = wtb + ((kind == 0) ? W1T_E : (kind == 1) ? WOUTT_E : W0T_E);
            float bn0 = (kind == 0) ? b0a : (kind == 1) ? b1a : (kind == 2) ? bta : bha;
            float bn1 = (kind == 0) ? b0b : (kind == 1) ? b1b : (kind == 2) ? btb : bhb;
            f32x4 acc[2][2];
#pragma unroll
            for (int m = 0; m < 2; m++) { acc[m][0] = f32x4{0.f,0.f,0.f,0.f}; acc[m][1] = f32x4{0.f,0.f,0.f,0.f}; }
            mmul<2, 8>(Alds, tread, lane, wv, acc);
            float bn[2] = {bn0, bn1};
#pragma unroll
            for (int n = 0; n < 2; n++) {
                int c = wv*32 + n*16 + mr;
#pragma unroll
                for (int m = 0; m < 2; m++) {
                    int jl = m*16 + q*4;
#pragma unroll
                    for (int rr2 = 0; rr2 < 4; rr2++) {
                        int jr = jl + rr2;
                        float s = acc[m][n][rr2] + bn[n];
                        float xv;
                        if (kind <= 1) {
                            xv = tanh_fast(s);
                        } else if (kind == 2) {
                            xv = hsL[lsx(jr, c)] + 0.25f*s;
                            hsL[lsx(jr, c)] = xv;
                        } else {
                            float cc = tanh_fast(s);
                            float hvv = hv1L[lsx(jr, c)];
                            xv = hvv + ob*zbL[lsx(jr, c)]*(cc - hvv);
                            hsL[lsx(jr, c)] = xv;
                        }
                        xh[jr*XH_STRIDE + c] = (short)f2b(xv);
                    }
                }
            }
            __syncthreads();
            smm<128, 128>(WT, 0, wv, q, mr, xh, wrT);
        }

        rd++;
        if (local) bar_local(flags, b, wg, rd + 1); else bar_global(flags, b, wg, rd + 1);
    }
}

extern "C" void kernel_launch(void* const* d_in, const int* in_sizes, int n_in,
                              void* d_out, int out_size, void* d_ws, size_t ws_size,
                              hipStream_t stream) {
    (void)in_sizes; (void)n_in; (void)out_size; (void)ws_size;
    const float* vals = (const float*)d_in[0];
    const float* msk  = (const float*)d_in[1];
    const float* A    = (const float*)d_in[2];
    const float* h0   = (const float*)d_in[3];
    const float* W0   = (const float*)d_in[4];
    const float* b0   = (const float*)d_in[5];
    const float* W1   = (const float*)d_in[6];
    const float* b1   = (const float*)d_in[7];
    const float* Wout = (const float*)d_in[8];
    const float* bout = (const float*)d_in[9];
    const float* Wz   = (const float*)d_in[10];
    const float* bz   = (const float*)d_in[11];
    const float* Wr   = (const float*)d_in[12];
    const float* br   = (const float*)d_in[13];
    const float* Wh   = (const float*)d_in[14];
    const float* bh   = (const float*)d_in[15];
    const float* Wo   = (const float*)d_in[16];
    const float* bo   = (const float*)d_in[17];

    char* ws = (char*)d_ws;
    int*   flags = (int*)(ws + FLAGS_OFF);
    float* obs   = (float*)(ws + OBS_OFF);
    int*   cnt   = (int*)(ws + XCD_OFF);
    short* wtb   = (short*)(ws + WT_OFF);
    short* tb    = (short*)(ws + TB_OFF);

    hipMemsetAsync(ws, 0, 40*1024, stream);   // round flags + setup flags + obs + cnt
    prep_wt<<<(WT_TOTAL + 255)/256, 256, 0, stream>>>(W0, W1, Wout, Wz, Wr, Wh, Wo, wtb);
    prep_obs<<<NBAT*TT, 256, 0, stream>>>(msk, obs);

    hipFuncSetAttribute((const void*)gcode_persist,
                        hipFuncAttributeMaxDynamicSharedMemorySize, LDS_BYTES);
    gcode_persist<<<256, 256, LDS_BYTES, stream>>>(
        A, vals, msk, h0, b0, b1, bout, bz, br, bh, bo,
        wtb, tb, obs, flags, cnt, (float*)d_out);
}